// Round 1
// baseline (663.816 us; speedup 1.0000x reference)
//
#include <hip/hip_runtime.h>
#include <hip/hip_bf16.h>
#include <cstddef>

#define QLEN 43054
#define DMODEL 256

// ---------------------------------------------------------------------------
// Generic f32 GEMM with bias: C[M,N] = A[M,K] @ W[K,N] + bias[N]
// 64x64 tile, BK=16, 256 threads, 4x4 microtile per thread.
// ---------------------------------------------------------------------------
__global__ __launch_bounds__(256) void gemm_bias_f32(
    const float* __restrict__ A, const float* __restrict__ W,
    const float* __restrict__ bias, float* __restrict__ C,
    int M, int N, int K)
{
    __shared__ float As[16][68];   // As[k][m]  (68 = 64+4 pad, keeps 16B align)
    __shared__ float Bs[16][68];   // Bs[k][n]

    const int tid = threadIdx.x;
    const int tx = tid & 15;          // col group 0..15
    const int ty = tid >> 4;          // row group 0..15
    const int block_m = blockIdx.x * 64;
    const int block_n = blockIdx.y * 64;

    // A-tile load mapping: each thread loads one float4 (4 consecutive k)
    const int ar = tid >> 2;          // 0..63 row within tile
    const int ak = (tid & 3) * 4;     // 0,4,8,12
    // B-tile load mapping: each thread loads one float4 (4 consecutive n)
    const int bk = tid >> 4;          // 0..15 k within tile
    const int bn = (tid & 15) * 4;    // 0..60

    float acc[4][4];
    #pragma unroll
    for (int i = 0; i < 4; ++i)
        #pragma unroll
        for (int j = 0; j < 4; ++j) acc[i][j] = 0.f;

    for (int k0 = 0; k0 < K; k0 += 16) {
        // load A tile (64 rows x 16 k), transposed into As[k][m]
        const int arow = block_m + ar;
        float4 av;
        if (arow < M) av = *(const float4*)(A + (size_t)arow * K + k0 + ak);
        else          av = make_float4(0.f, 0.f, 0.f, 0.f);
        As[ak + 0][ar] = av.x;
        As[ak + 1][ar] = av.y;
        As[ak + 2][ar] = av.z;
        As[ak + 3][ar] = av.w;
        // load B tile (16 k x 64 n)
        float4 bv4 = *(const float4*)(W + (size_t)(k0 + bk) * N + block_n + bn);
        *(float4*)&Bs[bk][bn] = bv4;
        __syncthreads();

        #pragma unroll
        for (int kk = 0; kk < 16; ++kk) {
            float a[4], b[4];
            *(float4*)a = *(const float4*)&As[kk][ty * 4];
            *(float4*)b = *(const float4*)&Bs[kk][tx * 4];
            #pragma unroll
            for (int i = 0; i < 4; ++i)
                #pragma unroll
                for (int j = 0; j < 4; ++j)
                    acc[i][j] = fmaf(a[i], b[j], acc[i][j]);
        }
        __syncthreads();
    }

    const float4 bb = *(const float4*)(bias + block_n + tx * 4);
    const float badd[4] = {bb.x, bb.y, bb.z, bb.w};
    #pragma unroll
    for (int i = 0; i < 4; ++i) {
        const int row = block_m + ty * 4 + i;
        if (row < M) {
            float4 o;
            o.x = acc[i][0] + badd[0];
            o.y = acc[i][1] + badd[1];
            o.z = acc[i][2] + badd[2];
            o.w = acc[i][3] + badd[3];
            *(float4*)(C + (size_t)row * N + block_n + tx * 4) = o;
        }
    }
}

// ---------------------------------------------------------------------------
// Fused softmax + multi-scale deformable sampling.
// One wave (64 lanes) per (q, h): lanes = 2 points x 32 channels.
// value : [LEN][8][32] f32      offs : [LEN][8][4][4][2] f32
// attl  : [LEN][8][16] f32      refp : [LEN][4][2] f32
// tmp   : [LEN][8][32] f32  (== [LEN][256] in q-major, head-major order)
// ---------------------------------------------------------------------------
__global__ __launch_bounds__(256) void msda_sample(
    const float* __restrict__ value,
    const float* __restrict__ offs,
    const float* __restrict__ attl,
    const float* __restrict__ refp,
    float* __restrict__ tmp)
{
    const int wv = (blockIdx.x << 2) + (threadIdx.x >> 6);
    const int lane = threadIdx.x & 63;
    const int q = wv >> 3;
    const int h = wv & 7;
    if (q >= QLEN) return;

    const int half = lane >> 5;   // which point of the pair
    const int d = lane & 31;      // channel within head

    // per-lane copies of this (q,h)'s 32 offsets and 16 logits
    const float offv  = offs[(size_t)q * 256 + h * 32 + (lane & 31)];
    const float logit = attl[(size_t)q * 128 + h * 16 + (lane & 15)];

    // softmax over the 16 logits (butterfly within 16-lane groups; all
    // four groups hold identical copies, so every lane gets the result)
    float mx = logit;
    #pragma unroll
    for (int msk = 1; msk < 16; msk <<= 1) mx = fmaxf(mx, __shfl_xor(mx, msk));
    float e = __expf(logit - mx);
    float sm = e;
    #pragma unroll
    for (int msk = 1; msk < 16; msk <<= 1) sm += __shfl_xor(sm, msk);
    const float attw = e / sm;

    const float* vb = value + (size_t)h * 32 + d;  // channel column base

    float acc = 0.f;
    #pragma unroll
    for (int it = 0; it < 8; ++it) {
        const int lvl = it >> 1;              // compile-time under unroll
        const int LW = (lvl == 0 ? 180 : lvl == 1 ? 90 : lvl == 2 ? 45 : 23);
        const int LS = (lvl == 0 ? 0 : lvl == 1 ? 32400 : lvl == 2 ? 40500 : 42525);

        const int pt = (it << 1) + half;      // 0..15, this half-wave's point
        const float ox = __shfl(offv, pt * 2);
        const float oy = __shfl(offv, pt * 2 + 1);
        const float aw = __shfl(attw, pt);
        const float rx = refp[((size_t)q * 4 + lvl) * 2 + 0];
        const float ry = refp[((size_t)q * 4 + lvl) * 2 + 1];

        // x = (rx + ox/W)*W - 0.5 == rx*W + ox - 0.5   (levels are square)
        const float x = fmaf(rx, (float)LW, ox) - 0.5f;
        const float y = fmaf(ry, (float)LW, oy) - 0.5f;
        const float x0f = floorf(x);
        const float y0f = floorf(y);
        const float dx = x - x0f;
        const float dy = y - y0f;
        const int x0 = (int)x0f;
        const int y0 = (int)y0f;

        const bool xin0 = (x0 >= 0) && (x0 < LW);
        const bool xin1 = (x0 + 1 >= 0) && (x0 + 1 < LW);
        const bool yin0 = (y0 >= 0) && (y0 < LW);
        const bool yin1 = (y0 + 1 >= 0) && (y0 + 1 < LW);

        float v00 = 0.f, v10 = 0.f, v01 = 0.f, v11 = 0.f;
        if (yin0) {
            const size_t rb = (size_t)(LS + y0 * LW) * 256;
            if (xin0) v00 = vb[rb + (size_t)x0 * 256];
            if (xin1) v10 = vb[rb + (size_t)(x0 + 1) * 256];
        }
        if (yin1) {
            const size_t rb = (size_t)(LS + (y0 + 1) * LW) * 256;
            if (xin0) v01 = vb[rb + (size_t)x0 * 256];
            if (xin1) v11 = vb[rb + (size_t)(x0 + 1) * 256];
        }

        const float wx0 = 1.f - dx, wx1 = dx;
        const float wy0 = 1.f - dy, wy1 = dy;
        const float sv = (v00 * wx0 + v10 * wx1) * wy0
                       + (v01 * wx0 + v11 * wx1) * wy1;
        acc = fmaf(aw, sv, acc);
    }

    // combine the two point-halves
    acc += __shfl_xor(acc, 32);
    if (half == 0) tmp[(size_t)q * 256 + h * 32 + d] = acc;
}

// ---------------------------------------------------------------------------
extern "C" void kernel_launch(void* const* d_in, const int* in_sizes, int n_in,
                              void* d_out, int out_size, void* d_ws, size_t ws_size,
                              hipStream_t stream)
{
    const float* query    = (const float*)d_in[0];
    const float* value_in = (const float*)d_in[1];
    const float* refp     = (const float*)d_in[2];
    const float* Wv = (const float*)d_in[3];
    const float* bv = (const float*)d_in[4];
    const float* Ws = (const float*)d_in[5];
    const float* bs = (const float*)d_in[6];
    const float* Wa = (const float*)d_in[7];
    const float* ba = (const float*)d_in[8];
    const float* Wo = (const float*)d_in[9];
    const float* bo = (const float*)d_in[10];
    float* out = (float*)d_out;

    float* value = (float*)d_ws;                       // LEN*256 f32
    float* offs  = value + (size_t)QLEN * 256;         // LEN*256 f32
    float* attl  = offs  + (size_t)QLEN * 256;         // LEN*128 f32
    float* tmp   = attl  + (size_t)QLEN * 128;         // LEN*256 f32

    const dim3 blk(256);
    const int mt = (QLEN + 63) / 64;                   // 673

    gemm_bias_f32<<<dim3(mt, 4), blk, 0, stream>>>(value_in, Wv, bv, value, QLEN, 256, 256);
    gemm_bias_f32<<<dim3(mt, 4), blk, 0, stream>>>(query,    Ws, bs, offs,  QLEN, 256, 256);
    gemm_bias_f32<<<dim3(mt, 2), blk, 0, stream>>>(query,    Wa, ba, attl,  QLEN, 128, 256);

    const int nwaves = QLEN * 8;
    msda_sample<<<dim3((nwaves + 3) / 4), blk, 0, stream>>>(value, offs, attl, refp, tmp);

    gemm_bias_f32<<<dim3(mt, 4), blk, 0, stream>>>(tmp, Wo, bo, out, QLEN, 256, 256);
}

// Round 2
// 571.012 us; speedup vs baseline: 1.1625x; 1.1625x over previous
//
#include <hip/hip_runtime.h>
#include <hip/hip_bf16.h>
#include <cstddef>

#define QLEN 43054
#define DMODEL 256

// ---------------------------------------------------------------------------
// Generic f32 GEMM with bias: C[M,N] = A[M,K] @ W[K,N] + bias[N]
// 64x64 tile, BK=16, 256 threads, 4x4 microtile per thread.
// ---------------------------------------------------------------------------
__global__ __launch_bounds__(256) void gemm_bias_f32(
    const float* __restrict__ A, const float* __restrict__ W,
    const float* __restrict__ bias, float* __restrict__ C,
    int M, int N, int K)
{
    __shared__ float As[16][68];   // As[k][m]  (68 = 64+4 pad, keeps 16B align)
    __shared__ float Bs[16][68];   // Bs[k][n]

    const int tid = threadIdx.x;
    const int tx = tid & 15;          // col group 0..15
    const int ty = tid >> 4;          // row group 0..15
    const int block_m = blockIdx.x * 64;
    const int block_n = blockIdx.y * 64;

    const int ar = tid >> 2;          // 0..63 row within tile
    const int ak = (tid & 3) * 4;     // 0,4,8,12
    const int bk = tid >> 4;          // 0..15 k within tile
    const int bn = (tid & 15) * 4;    // 0..60

    float acc[4][4];
    #pragma unroll
    for (int i = 0; i < 4; ++i)
        #pragma unroll
        for (int j = 0; j < 4; ++j) acc[i][j] = 0.f;

    for (int k0 = 0; k0 < K; k0 += 16) {
        const int arow = block_m + ar;
        float4 av;
        if (arow < M) av = *(const float4*)(A + (size_t)arow * K + k0 + ak);
        else          av = make_float4(0.f, 0.f, 0.f, 0.f);
        As[ak + 0][ar] = av.x;
        As[ak + 1][ar] = av.y;
        As[ak + 2][ar] = av.z;
        As[ak + 3][ar] = av.w;
        float4 bv4 = *(const float4*)(W + (size_t)(k0 + bk) * N + block_n + bn);
        *(float4*)&Bs[bk][bn] = bv4;
        __syncthreads();

        #pragma unroll
        for (int kk = 0; kk < 16; ++kk) {
            float a[4], b[4];
            *(float4*)a = *(const float4*)&As[kk][ty * 4];
            *(float4*)b = *(const float4*)&Bs[kk][tx * 4];
            #pragma unroll
            for (int i = 0; i < 4; ++i)
                #pragma unroll
                for (int j = 0; j < 4; ++j)
                    acc[i][j] = fmaf(a[i], b[j], acc[i][j]);
        }
        __syncthreads();
    }

    const float4 bb = *(const float4*)(bias + block_n + tx * 4);
    const float badd[4] = {bb.x, bb.y, bb.z, bb.w};
    #pragma unroll
    for (int i = 0; i < 4; ++i) {
        const int row = block_m + ty * 4 + i;
        if (row < M) {
            float4 o;
            o.x = acc[i][0] + badd[0];
            o.y = acc[i][1] + badd[1];
            o.z = acc[i][2] + badd[2];
            o.w = acc[i][3] + badd[3];
            *(float4*)(C + (size_t)row * N + block_n + tx * 4) = o;
        }
    }
}

// ---------------------------------------------------------------------------
// Fused softmax + multi-scale deformable sampling, v2.
// One wave (64 lanes) per (q, h): lanes = 16 points x 4 channel-octets.
// Each lane: 1 point, 8 channels (2x float4 per corner), 32 combine-FMAs.
// value : [LEN][8][32] f32      offs : [LEN][8][4][4][2] f32
// attl  : [LEN][8][16] f32      refp : [LEN][4][2] f32
// tmp   : [LEN][8][32] f32
// ---------------------------------------------------------------------------
__device__ __forceinline__ float4 fma4(float w, float4 v, float4 a) {
    a.x = fmaf(w, v.x, a.x);
    a.y = fmaf(w, v.y, a.y);
    a.z = fmaf(w, v.z, a.z);
    a.w = fmaf(w, v.w, a.w);
    return a;
}

__global__ __launch_bounds__(256) void msda_sample(
    const float* __restrict__ value,
    const float* __restrict__ offs,
    const float* __restrict__ attl,
    const float* __restrict__ refp,
    float* __restrict__ tmp)
{
    const int wv = (blockIdx.x << 2) + (threadIdx.x >> 6);
    const int lane = threadIdx.x & 63;
    const int q = wv >> 3;
    const int h = wv & 7;
    if (q >= QLEN) return;

    const int g = lane >> 2;      // point index 0..15  (level = g>>2)
    const int j = lane & 3;       // channel octet: channels 8j..8j+7

    // cooperative loads of this (q,h)'s parameters
    const float offv  = offs[(size_t)q * 256 + h * 32 + (lane & 31)];
    const float logit = attl[(size_t)q * 128 + h * 16 + (lane & 15)];
    const float refv  = refp[(size_t)q * 8 + (lane & 7)];

    // softmax over 16 logits (all 16-lane groups hold identical copies)
    float mx = logit;
    #pragma unroll
    for (int msk = 1; msk < 16; msk <<= 1) mx = fmaxf(mx, __shfl_xor(mx, msk));
    const float e = __expf(logit - mx);
    float sm = e;
    #pragma unroll
    for (int msk = 1; msk < 16; msk <<= 1) sm += __shfl_xor(sm, msk);
    const float attw = e / sm;

    // per-lane level constants
    const int lvl = g >> 2;
    const int LW = (lvl == 0) ? 180 : (lvl == 1) ? 90 : (lvl == 2) ? 45 : 23;
    const int LS = (lvl == 0) ? 0 : (lvl == 1) ? 32400 : (lvl == 2) ? 40500 : 42525;

    // gather this lane's point parameters
    const float ox = __shfl(offv, g * 2);
    const float oy = __shfl(offv, g * 2 + 1);
    const float aw = __shfl(attw, g);
    const float rx = __shfl(refv, lvl * 2);
    const float ry = __shfl(refv, lvl * 2 + 1);

    // x = (rx + ox/W)*W - 0.5 == rx*W + ox - 0.5 (square levels)
    const float fLW = (float)LW;
    const float x = fmaf(rx, fLW, ox) - 0.5f;
    const float y = fmaf(ry, fLW, oy) - 0.5f;
    const float x0f = floorf(x), y0f = floorf(y);
    const float dx = x - x0f, dy = y - y0f;
    const int x0 = (int)x0f, y0 = (int)y0f;
    const int x1 = x0 + 1, y1 = y0 + 1;

    const bool vx0 = (x0 >= 0) && (x0 < LW);
    const bool vx1 = (x1 >= 0) && (x1 < LW);
    const bool vy0 = (y0 >= 0) && (y0 < LW);
    const bool vy1 = (y1 >= 0) && (y1 < LW);

    const int x0c = min(max(x0, 0), LW - 1);
    const int x1c = min(max(x1, 0), LW - 1);
    const int y0c = min(max(y0, 0), LW - 1);
    const int y1c = min(max(y1, 0), LW - 1);

    const float wx0 = 1.f - dx, wy0 = 1.f - dy;
    float w00 = wx0 * wy0 * aw;
    float w10 = dx  * wy0 * aw;
    float w01 = wx0 * dy  * aw;
    float w11 = dx  * dy  * aw;
    w00 = (vx0 && vy0) ? w00 : 0.f;
    w10 = (vx1 && vy0) ? w10 : 0.f;
    w01 = (vx0 && vy1) ? w01 : 0.f;
    w11 = (vx1 && vy1) ? w11 : 0.f;

    // addresses (float4 units): pixel p -> p*64 + h*8 + j*2
    const float4* __restrict__ V4 = (const float4*)value;
    const int boff = h * 8 + j * 2;
    const int r0 = LS + y0c * LW;
    const int r1 = LS + y1c * LW;
    const size_t i00 = (size_t)(r0 + x0c) * 64 + boff;
    const size_t i10 = (size_t)(r0 + x1c) * 64 + boff;
    const size_t i01 = (size_t)(r1 + x0c) * 64 + boff;
    const size_t i11 = (size_t)(r1 + x1c) * 64 + boff;

    const float4 a00 = V4[i00],     b00 = V4[i00 + 1];
    const float4 a10 = V4[i10],     b10 = V4[i10 + 1];
    const float4 a01 = V4[i01],     b01 = V4[i01 + 1];
    const float4 a11 = V4[i11],     b11 = V4[i11 + 1];

    float4 accA = make_float4(0.f, 0.f, 0.f, 0.f);
    float4 accB = make_float4(0.f, 0.f, 0.f, 0.f);
    accA = fma4(w00, a00, accA);  accB = fma4(w00, b00, accB);
    accA = fma4(w10, a10, accA);  accB = fma4(w10, b10, accB);
    accA = fma4(w01, a01, accA);  accB = fma4(w01, b01, accB);
    accA = fma4(w11, a11, accA);  accB = fma4(w11, b11, accB);

    // reduce across the 16 point-groups (lanes with equal j, xor 4/8/16/32)
    #pragma unroll
    for (int msk = 4; msk <= 32; msk <<= 1) {
        accA.x += __shfl_xor(accA.x, msk);
        accA.y += __shfl_xor(accA.y, msk);
        accA.z += __shfl_xor(accA.z, msk);
        accA.w += __shfl_xor(accA.w, msk);
        accB.x += __shfl_xor(accB.x, msk);
        accB.y += __shfl_xor(accB.y, msk);
        accB.z += __shfl_xor(accB.z, msk);
        accB.w += __shfl_xor(accB.w, msk);
    }

    if (g == 0) {
        float4* T4 = (float4*)tmp;
        const size_t ob = (size_t)q * 64 + h * 8 + j * 2;
        T4[ob]     = accA;
        T4[ob + 1] = accB;
    }
}

// ---------------------------------------------------------------------------
extern "C" void kernel_launch(void* const* d_in, const int* in_sizes, int n_in,
                              void* d_out, int out_size, void* d_ws, size_t ws_size,
                              hipStream_t stream)
{
    const float* query    = (const float*)d_in[0];
    const float* value_in = (const float*)d_in[1];
    const float* refp     = (const float*)d_in[2];
    const float* Wv = (const float*)d_in[3];
    const float* bv = (const float*)d_in[4];
    const float* Ws = (const float*)d_in[5];
    const float* bs = (const float*)d_in[6];
    const float* Wa = (const float*)d_in[7];
    const float* ba = (const float*)d_in[8];
    const float* Wo = (const float*)d_in[9];
    const float* bo = (const float*)d_in[10];
    float* out = (float*)d_out;

    float* value = (float*)d_ws;                       // LEN*256 f32
    float* offs  = value + (size_t)QLEN * 256;         // LEN*256 f32
    float* attl  = offs  + (size_t)QLEN * 256;         // LEN*128 f32
    float* tmp   = attl  + (size_t)QLEN * 128;         // LEN*256 f32

    const dim3 blk(256);
    const int mt = (QLEN + 63) / 64;                   // 673

    gemm_bias_f32<<<dim3(mt, 4), blk, 0, stream>>>(value_in, Wv, bv, value, QLEN, 256, 256);
    gemm_bias_f32<<<dim3(mt, 4), blk, 0, stream>>>(query,    Ws, bs, offs,  QLEN, 256, 256);
    gemm_bias_f32<<<dim3(mt, 2), blk, 0, stream>>>(query,    Wa, ba, attl,  QLEN, 128, 256);

    const int nwaves = QLEN * 8;
    msda_sample<<<dim3((nwaves + 3) / 4), blk, 0, stream>>>(value, offs, attl, refp, tmp);

    gemm_bias_f32<<<dim3(mt, 4), blk, 0, stream>>>(tmp, Wo, bo, out, QLEN, 256, 256);
}

// Round 3
// 464.871 us; speedup vs baseline: 1.4280x; 1.2283x over previous
//
#include <hip/hip_runtime.h>
#include <hip/hip_bf16.h>
#include <cstddef>

#define QLEN 43054

typedef __attribute__((ext_vector_type(8))) short short8;
typedef __attribute__((ext_vector_type(8))) unsigned short ushort8;
typedef __attribute__((ext_vector_type(4))) float f32x4;

__device__ __forceinline__ unsigned short f32_to_bf16_rne(float f) {
    unsigned int u = __float_as_uint(f);
    unsigned int r = (u + 0x7fffu + ((u >> 16) & 1u)) >> 16;
    return (unsigned short)r;
}
__device__ __forceinline__ float bf16_to_f32(unsigned short h) {
    return __uint_as_float(((unsigned int)h) << 16);
}

// ---------------------------------------------------------------------------
// Transpose + hi/lo split of a weight matrix W[K=256][N] -> Wt_hi/lo[N][256]
// ---------------------------------------------------------------------------
__global__ __launch_bounds__(256) void w_split(
    const float* __restrict__ W, unsigned short* __restrict__ hi,
    unsigned short* __restrict__ lo, int N)
{
    const int t = blockIdx.x * 256 + threadIdx.x;   // grid = N blocks
    const int n = t >> 8;
    const int k = t & 255;
    const float w = W[(size_t)k * N + n];
    const unsigned short h = f32_to_bf16_rne(w);
    const float rem = w - bf16_to_f32(h);
    hi[(size_t)n * 256 + k] = h;
    lo[(size_t)n * 256 + k] = f32_to_bf16_rne(rem);
}

// ---------------------------------------------------------------------------
// f32 -> bf16 (RNE), vectorized: n4 float4-units
// ---------------------------------------------------------------------------
__global__ __launch_bounds__(256) void cvt_bf16(
    const float* __restrict__ in, unsigned short* __restrict__ out, int n4)
{
    int i = blockIdx.x * 256 + threadIdx.x;
    const int stride = gridDim.x * 256;
    for (; i < n4; i += stride) {
        const float4 v = ((const float4*)in)[i];
        ushort4 o;
        o.x = f32_to_bf16_rne(v.x);
        o.y = f32_to_bf16_rne(v.y);
        o.z = f32_to_bf16_rne(v.z);
        o.w = f32_to_bf16_rne(v.w);
        ((ushort4*)out)[i] = o;
    }
}

// ---------------------------------------------------------------------------
// Direct-fragment MFMA GEMM: C[M,N] = A_bf16[M,256] @ (Bh+Bl)[256,N] + bias
// Block 128x128 (4 waves, 2x2 of 64x64). No LDS. K fixed = 256.
// Wt layout: [N][256] bf16 (hi and lo). mode 0: f32 out (ld N); mode 1: bf16
// out (ld 256).
// ---------------------------------------------------------------------------
__global__ __launch_bounds__(256) void gemm_mfma(
    const unsigned short* __restrict__ A,
    const unsigned short* __restrict__ Bh,
    const unsigned short* __restrict__ Bl,
    const float* __restrict__ bias,
    float* __restrict__ Cf, unsigned short* __restrict__ Cb,
    int M, int N, int mode)
{
    const int lane = threadIdx.x & 63;
    const int w = threadIdx.x >> 6;
    const int wm = (w >> 1) * 64;
    const int wn = (w & 1) * 64;
    const int bm = blockIdx.x * 128;
    const int bn = blockIdx.y * 128;
    const int lr = lane & 15;
    const int lk = (lane >> 4) * 8;

    const unsigned short* aptr[4];
    const unsigned short* bhptr[4];
    const unsigned short* blptr[4];
    #pragma unroll
    for (int f = 0; f < 4; ++f) {
        int row = bm + wm + f * 16 + lr;
        row = min(row, M - 1);
        aptr[f] = A + (size_t)row * 256 + lk;
        const int col = bn + wn + f * 16 + lr;
        bhptr[f] = Bh + (size_t)col * 256 + lk;
        blptr[f] = Bl + (size_t)col * 256 + lk;
    }

    f32x4 acc[4][4];
    #pragma unroll
    for (int i = 0; i < 4; ++i)
        #pragma unroll
        for (int j = 0; j < 4; ++j)
            acc[i][j] = (f32x4){0.f, 0.f, 0.f, 0.f};

    #pragma unroll 2
    for (int k0 = 0; k0 < 256; k0 += 32) {
        short8 a[4], bh[4], bl[4];
        #pragma unroll
        for (int f = 0; f < 4; ++f) {
            a[f]  = *(const short8*)(aptr[f] + k0);
            bh[f] = *(const short8*)(bhptr[f] + k0);
            bl[f] = *(const short8*)(blptr[f] + k0);
        }
        #pragma unroll
        for (int i = 0; i < 4; ++i)
            #pragma unroll
            for (int j = 0; j < 4; ++j) {
                acc[i][j] = __builtin_amdgcn_mfma_f32_16x16x32_bf16(a[i], bh[j], acc[i][j], 0, 0, 0);
                acc[i][j] = __builtin_amdgcn_mfma_f32_16x16x32_bf16(a[i], bl[j], acc[i][j], 0, 0, 0);
            }
    }

    float bv[4];
    #pragma unroll
    for (int j = 0; j < 4; ++j) bv[j] = bias[bn + wn + j * 16 + lr];

    const int rbase = bm + wm + (lane >> 4) * 4;
    if (mode == 0) {
        #pragma unroll
        for (int i = 0; i < 4; ++i)
            #pragma unroll
            for (int r = 0; r < 4; ++r) {
                const int row = rbase + i * 16 + r;
                if (row < M) {
                    #pragma unroll
                    for (int j = 0; j < 4; ++j) {
                        const int col = bn + wn + j * 16 + lr;
                        Cf[(size_t)row * N + col] = acc[i][j][r] + bv[j];
                    }
                }
            }
    } else {
        #pragma unroll
        for (int i = 0; i < 4; ++i)
            #pragma unroll
            for (int r = 0; r < 4; ++r) {
                const int row = rbase + i * 16 + r;
                if (row < M) {
                    #pragma unroll
                    for (int j = 0; j < 4; ++j) {
                        const int col = bn + wn + j * 16 + lr;
                        Cb[(size_t)row * 256 + col] = f32_to_bf16_rne(acc[i][j][r] + bv[j]);
                    }
                }
            }
    }
}

// ---------------------------------------------------------------------------
// Fused softmax + multi-scale deformable sampling, v3 (bf16 value/tmp).
// One wave per (q,h): lanes = 16 points x 4 channel-octets.
// value : [LEN][8][32] bf16     offs : [LEN][8][4][4][2] f32
// attl  : [LEN][8][16] f32      refp : [LEN][4][2] f32
// tmp   : [LEN][8][32] bf16
// ---------------------------------------------------------------------------
__global__ __launch_bounds__(256) void msda_sample(
    const unsigned short* __restrict__ value,
    const float* __restrict__ offs,
    const float* __restrict__ attl,
    const float* __restrict__ refp,
    unsigned short* __restrict__ tmp)
{
    const int wv = (blockIdx.x << 2) + (threadIdx.x >> 6);
    const int lane = threadIdx.x & 63;
    const int q = wv >> 3;
    const int h = wv & 7;
    if (q >= QLEN) return;

    const int g = lane >> 2;      // point index 0..15  (level = g>>2)
    const int j = lane & 3;       // channel octet: channels 8j..8j+7

    const float offv  = offs[(size_t)q * 256 + h * 32 + (lane & 31)];
    const float logit = attl[(size_t)q * 128 + h * 16 + (lane & 15)];
    const float refv  = refp[(size_t)q * 8 + (lane & 7)];

    // softmax over 16 logits (all 16-lane groups hold identical copies)
    float mx = logit;
    #pragma unroll
    for (int msk = 1; msk < 16; msk <<= 1) mx = fmaxf(mx, __shfl_xor(mx, msk));
    const float e = __expf(logit - mx);
    float sm = e;
    #pragma unroll
    for (int msk = 1; msk < 16; msk <<= 1) sm += __shfl_xor(sm, msk);
    const float attw = e / sm;

    const int lvl = g >> 2;
    const int LW = (lvl == 0) ? 180 : (lvl == 1) ? 90 : (lvl == 2) ? 45 : 23;
    const int LS = (lvl == 0) ? 0 : (lvl == 1) ? 32400 : (lvl == 2) ? 40500 : 42525;

    const float ox = __shfl(offv, g * 2);
    const float oy = __shfl(offv, g * 2 + 1);
    const float aw = __shfl(attw, g);
    const float rx = __shfl(refv, lvl * 2);
    const float ry = __shfl(refv, lvl * 2 + 1);

    const float fLW = (float)LW;
    const float x = fmaf(rx, fLW, ox) - 0.5f;
    const float y = fmaf(ry, fLW, oy) - 0.5f;
    const float x0f = floorf(x), y0f = floorf(y);
    const float dx = x - x0f, dy = y - y0f;
    const int x0 = (int)x0f, y0 = (int)y0f;
    const int x1 = x0 + 1, y1 = y0 + 1;

    const bool vx0 = (x0 >= 0) && (x0 < LW);
    const bool vx1 = (x1 >= 0) && (x1 < LW);
    const bool vy0 = (y0 >= 0) && (y0 < LW);
    const bool vy1 = (y1 >= 0) && (y1 < LW);

    const int x0c = min(max(x0, 0), LW - 1);
    const int x1c = min(max(x1, 0), LW - 1);
    const int y0c = min(max(y0, 0), LW - 1);
    const int y1c = min(max(y1, 0), LW - 1);

    const float wx0 = 1.f - dx, wy0 = 1.f - dy;
    float w00 = wx0 * wy0 * aw;
    float w10 = dx  * wy0 * aw;
    float w01 = wx0 * dy  * aw;
    float w11 = dx  * dy  * aw;
    w00 = (vx0 && vy0) ? w00 : 0.f;
    w10 = (vx1 && vy0) ? w10 : 0.f;
    w01 = (vx0 && vy1) ? w01 : 0.f;
    w11 = (vx1 && vy1) ? w11 : 0.f;

    // bf16 value: pixel p -> element offset p*256 + h*32 + j*8
    const unsigned short* __restrict__ vb = value + h * 32 + j * 8;
    const int r0 = LS + y0c * LW;
    const int r1 = LS + y1c * LW;
    const ushort8 v00 = *(const ushort8*)(vb + (size_t)(r0 + x0c) * 256);
    const ushort8 v10 = *(const ushort8*)(vb + (size_t)(r0 + x1c) * 256);
    const ushort8 v01 = *(const ushort8*)(vb + (size_t)(r1 + x0c) * 256);
    const ushort8 v11 = *(const ushort8*)(vb + (size_t)(r1 + x1c) * 256);

    float acc[8];
    #pragma unroll
    for (int e = 0; e < 8; ++e) {
        float s = w00 * bf16_to_f32(v00[e]);
        s = fmaf(w10, bf16_to_f32(v10[e]), s);
        s = fmaf(w01, bf16_to_f32(v01[e]), s);
        s = fmaf(w11, bf16_to_f32(v11[e]), s);
        acc[e] = s;
    }

    // reduce across the 16 point-groups
    #pragma unroll
    for (int msk = 4; msk <= 32; msk <<= 1)
        #pragma unroll
        for (int e = 0; e < 8; ++e)
            acc[e] += __shfl_xor(acc[e], msk);

    if (g == 0) {
        ushort8 o;
        #pragma unroll
        for (int e = 0; e < 8; ++e) o[e] = f32_to_bf16_rne(acc[e]);
        *(ushort8*)(tmp + (size_t)q * 256 + h * 32 + j * 8) = o;
    }
}

// ---------------------------------------------------------------------------
extern "C" void kernel_launch(void* const* d_in, const int* in_sizes, int n_in,
                              void* d_out, int out_size, void* d_ws, size_t ws_size,
                              hipStream_t stream)
{
    const float* query    = (const float*)d_in[0];
    const float* value_in = (const float*)d_in[1];
    const float* refp     = (const float*)d_in[2];
    const float* Wv = (const float*)d_in[3];
    const float* bv = (const float*)d_in[4];
    const float* Ws = (const float*)d_in[5];
    const float* bs = (const float*)d_in[6];
    const float* Wa = (const float*)d_in[7];
    const float* ba = (const float*)d_in[8];
    const float* Wo = (const float*)d_in[9];
    const float* bo = (const float*)d_in[10];
    float* out = (float*)d_out;

    // workspace layout (bytes)
    char* p = (char*)d_ws;
    const size_t SZ_BF = (size_t)QLEN * 256 * 2;   // 22,043,648
    unsigned short* q_bf   = (unsigned short*)p;               p += SZ_BF;
    unsigned short* vin_bf = (unsigned short*)p;               p += SZ_BF;  // reused as tmp_bf
    unsigned short* val_bf = (unsigned short*)p;               p += SZ_BF;
    float*          offs   = (float*)p;                        p += (size_t)QLEN * 256 * 4;
    float*          attl   = (float*)p;                        p += (size_t)QLEN * 128 * 4;
    unsigned short* wtv_h  = (unsigned short*)p;               p += 256 * 256 * 2;
    unsigned short* wtv_l  = (unsigned short*)p;               p += 256 * 256 * 2;
    unsigned short* wts_h  = (unsigned short*)p;               p += 256 * 256 * 2;
    unsigned short* wts_l  = (unsigned short*)p;               p += 256 * 256 * 2;
    unsigned short* wta_h  = (unsigned short*)p;               p += 128 * 256 * 2;
    unsigned short* wta_l  = (unsigned short*)p;               p += 128 * 256 * 2;
    unsigned short* wto_h  = (unsigned short*)p;               p += 256 * 256 * 2;
    unsigned short* wto_l  = (unsigned short*)p;               p += 256 * 256 * 2;
    unsigned short* tmp_bf = vin_bf;   // lifetime-disjoint reuse

    const dim3 blk(256);
    const int MT = (QLEN + 127) / 128;   // 337
    const int n4 = QLEN * 256 / 4;       // QLEN*256 divisible by 4

    // pre-passes
    w_split<<<256, blk, 0, stream>>>(Wv, wtv_h, wtv_l, 256);
    w_split<<<256, blk, 0, stream>>>(Ws, wts_h, wts_l, 256);
    w_split<<<128, blk, 0, stream>>>(Wa, wta_h, wta_l, 128);
    w_split<<<256, blk, 0, stream>>>(Wo, wto_h, wto_l, 256);
    cvt_bf16<<<1024, blk, 0, stream>>>(query,    q_bf,   n4);
    cvt_bf16<<<1024, blk, 0, stream>>>(value_in, vin_bf, n4);

    // GEMMs
    gemm_mfma<<<dim3(MT, 2), blk, 0, stream>>>(vin_bf, wtv_h, wtv_l, bv,
                                               nullptr, val_bf, QLEN, 256, 1);
    gemm_mfma<<<dim3(MT, 2), blk, 0, stream>>>(q_bf, wts_h, wts_l, bs,
                                               offs, nullptr, QLEN, 256, 0);
    gemm_mfma<<<dim3(MT, 1), blk, 0, stream>>>(q_bf, wta_h, wta_l, ba,
                                               attl, nullptr, QLEN, 128, 0);

    // sampler
    const int nwaves = QLEN * 8;
    msda_sample<<<dim3((nwaves + 3) / 4), blk, 0, stream>>>(val_bf, offs, attl, refp, tmp_bf);

    // output projection
    gemm_mfma<<<dim3(MT, 2), blk, 0, stream>>>(tmp_bf, wto_h, wto_l, bo,
                                               out, nullptr, QLEN, 256, 0);
}

// Round 4
// 411.742 us; speedup vs baseline: 1.6122x; 1.1290x over previous
//
#include <hip/hip_runtime.h>
#include <hip/hip_bf16.h>
#include <cstddef>

#define QLEN 43054

typedef __attribute__((ext_vector_type(8))) short short8;
typedef __attribute__((ext_vector_type(8))) unsigned short ushort8;
typedef __attribute__((ext_vector_type(4))) float f32x4;

__device__ __forceinline__ unsigned short f32_to_bf16_rne(float f) {
    unsigned int u = __float_as_uint(f);
    unsigned int r = (u + 0x7fffu + ((u >> 16) & 1u)) >> 16;
    return (unsigned short)r;
}
__device__ __forceinline__ float bf16_to_f32(unsigned short h) {
    return __uint_as_float(((unsigned int)h) << 16);
}

// ---------------------------------------------------------------------------
// Transpose + hi/lo split of a weight matrix W[K=256][N] -> Wt_hi/lo[N][256]
// ---------------------------------------------------------------------------
__global__ __launch_bounds__(256) void w_split(
    const float* __restrict__ W, unsigned short* __restrict__ hi,
    unsigned short* __restrict__ lo, int N)
{
    const int t = blockIdx.x * 256 + threadIdx.x;   // grid = N blocks
    const int n = t >> 8;
    const int k = t & 255;
    const float w = W[(size_t)k * N + n];
    const unsigned short h = f32_to_bf16_rne(w);
    const float rem = w - bf16_to_f32(h);
    hi[(size_t)n * 256 + k] = h;
    lo[(size_t)n * 256 + k] = f32_to_bf16_rne(rem);
}

// ---------------------------------------------------------------------------
// f32 -> bf16 (RNE), vectorized: n4 float4-units
// ---------------------------------------------------------------------------
__global__ __launch_bounds__(256) void cvt_bf16(
    const float* __restrict__ in, unsigned short* __restrict__ out, int n4)
{
    int i = blockIdx.x * 256 + threadIdx.x;
    const int stride = gridDim.x * 256;
    for (; i < n4; i += stride) {
        const float4 v = ((const float4*)in)[i];
        ushort4 o;
        o.x = f32_to_bf16_rne(v.x);
        o.y = f32_to_bf16_rne(v.y);
        o.z = f32_to_bf16_rne(v.z);
        o.w = f32_to_bf16_rne(v.w);
        ((ushort4*)out)[i] = o;
    }
}

// ---------------------------------------------------------------------------
// LDS-staged MFMA GEMM (m97 structure): C[M,N] = A_bf16[M,256] @ (Bh+Bl) + bias
// Block 128x128 (4 waves, 2x2 of 64x64), BK=32, K fixed = 256.
// A: [M][256] bf16 row-major.  Bh/Bl: [N][256] bf16 (pre-transposed weights).
// Staging via global_load_lds width=16 with XOR-swizzled source (rule #21):
// LDS slot (row, c) holds global element (row, c ^ ((row>>1)&3))  [c = 16B col]
// -> fragment ds_read_b128 lands at 2-way bank aliasing (free, m136).
// mode 0: f32 out (ld N); mode 1: bf16 out (ld 256).
// ---------------------------------------------------------------------------
__global__ __launch_bounds__(256) void gemm_mfma_lds(
    const unsigned short* __restrict__ A,
    const unsigned short* __restrict__ Bh,
    const unsigned short* __restrict__ Bl,
    const float* __restrict__ bias,
    float* __restrict__ Cf, unsigned short* __restrict__ Cb,
    int M, int N, int mode)
{
    __shared__ alignas(16) unsigned short As[128 * 32];
    __shared__ alignas(16) unsigned short Bhs[128 * 32];
    __shared__ alignas(16) unsigned short Bls[128 * 32];

    const int tid = threadIdx.x;
    const int lane = tid & 63;
    const int w = tid >> 6;
    const int wm = (w >> 1) * 64;
    const int wn = (w & 1) * 64;
    const int bm = blockIdx.x * 128;
    const int bn = blockIdx.y * 128;

    // staging mapping: issue ii = w*2+i covers LDS rows ii*16 .. ii*16+15
    const int rl = lane >> 2;        // row within issue (0..15)
    const int cd = lane & 3;         // dest 16B-column (0..3)

    // fragment-read mapping
    const int fr = lane & 15;
    const int fc = lane >> 4;

    f32x4 acc[4][4];
    #pragma unroll
    for (int i = 0; i < 4; ++i)
        #pragma unroll
        for (int j = 0; j < 4; ++j)
            acc[i][j] = (f32x4){0.f, 0.f, 0.f, 0.f};

    for (int k0 = 0; k0 < 256; k0 += 32) {
        #pragma unroll
        for (int i = 0; i < 2; ++i) {
            const int ii = w * 2 + i;
            const int row = ii * 16 + rl;
            const int cs = cd ^ ((row >> 1) & 3);       // swizzled source col
            const size_t gof = (size_t)(k0 + cs * 8);   // element offset in K
            const int ra = min(bm + row, M - 1);
            const int rb = bn + row;                    // N is multiple of 128
            __builtin_amdgcn_global_load_lds(
                (const unsigned int*)(A + (size_t)ra * 256 + gof),
                (unsigned int*)&As[ii * 512], 16, 0, 0);
            __builtin_amdgcn_global_load_lds(
                (const unsigned int*)(Bh + (size_t)rb * 256 + gof),
                (unsigned int*)&Bhs[ii * 512], 16, 0, 0);
            __builtin_amdgcn_global_load_lds(
                (const unsigned int*)(Bl + (size_t)rb * 256 + gof),
                (unsigned int*)&Bls[ii * 512], 16, 0, 0);
        }
        __syncthreads();   // compiler drains vmcnt before s_barrier (guide §5)

        short8 a[4], bh4[4], bl4[4];
        #pragma unroll
        for (int f = 0; f < 4; ++f) {
            const int rowA = wm + f * 16 + fr;
            const int pcA = fc ^ ((rowA >> 1) & 3);
            a[f] = *(const short8*)&As[rowA * 32 + pcA * 8];
            const int rowB = wn + f * 16 + fr;
            const int pcB = fc ^ ((rowB >> 1) & 3);
            bh4[f] = *(const short8*)&Bhs[rowB * 32 + pcB * 8];
            bl4[f] = *(const short8*)&Bls[rowB * 32 + pcB * 8];
        }

        #pragma unroll
        for (int i = 0; i < 4; ++i)
            #pragma unroll
            for (int j = 0; j < 4; ++j) {
                acc[i][j] = __builtin_amdgcn_mfma_f32_16x16x32_bf16(a[i], bh4[j], acc[i][j], 0, 0, 0);
                acc[i][j] = __builtin_amdgcn_mfma_f32_16x16x32_bf16(a[i], bl4[j], acc[i][j], 0, 0, 0);
            }
        __syncthreads();
    }

    float bv[4];
    #pragma unroll
    for (int j = 0; j < 4; ++j) bv[j] = bias[bn + wn + j * 16 + fr];

    const int rbase = bm + wm + fc * 4;
    if (mode == 0) {
        #pragma unroll
        for (int i = 0; i < 4; ++i)
            #pragma unroll
            for (int r = 0; r < 4; ++r) {
                const int row = rbase + i * 16 + r;
                if (row < M) {
                    #pragma unroll
                    for (int j = 0; j < 4; ++j) {
                        const int col = bn + wn + j * 16 + fr;
                        Cf[(size_t)row * N + col] = acc[i][j][r] + bv[j];
                    }
                }
            }
    } else {
        #pragma unroll
        for (int i = 0; i < 4; ++i)
            #pragma unroll
            for (int r = 0; r < 4; ++r) {
                const int row = rbase + i * 16 + r;
                if (row < M) {
                    #pragma unroll
                    for (int j = 0; j < 4; ++j) {
                        const int col = bn + wn + j * 16 + fr;
                        Cb[(size_t)row * 256 + col] = f32_to_bf16_rne(acc[i][j][r] + bv[j]);
                    }
                }
            }
    }
}

// ---------------------------------------------------------------------------
// Fused softmax + multi-scale deformable sampling, v3 (bf16 value/tmp).
// One wave per (q,h): lanes = 16 points x 4 channel-octets.  (unchanged)
// ---------------------------------------------------------------------------
__global__ __launch_bounds__(256) void msda_sample(
    const unsigned short* __restrict__ value,
    const float* __restrict__ offs,
    const float* __restrict__ attl,
    const float* __restrict__ refp,
    unsigned short* __restrict__ tmp)
{
    const int wv = (blockIdx.x << 2) + (threadIdx.x >> 6);
    const int lane = threadIdx.x & 63;
    const int q = wv >> 3;
    const int h = wv & 7;
    if (q >= QLEN) return;

    const int g = lane >> 2;      // point index 0..15  (level = g>>2)
    const int j = lane & 3;       // channel octet: channels 8j..8j+7

    const float offv  = offs[(size_t)q * 256 + h * 32 + (lane & 31)];
    const float logit = attl[(size_t)q * 128 + h * 16 + (lane & 15)];
    const float refv  = refp[(size_t)q * 8 + (lane & 7)];

    float mx = logit;
    #pragma unroll
    for (int msk = 1; msk < 16; msk <<= 1) mx = fmaxf(mx, __shfl_xor(mx, msk));
    const float e = __expf(logit - mx);
    float sm = e;
    #pragma unroll
    for (int msk = 1; msk < 16; msk <<= 1) sm += __shfl_xor(sm, msk);
    const float attw = e / sm;

    const int lvl = g >> 2;
    const int LW = (lvl == 0) ? 180 : (lvl == 1) ? 90 : (lvl == 2) ? 45 : 23;
    const int LS = (lvl == 0) ? 0 : (lvl == 1) ? 32400 : (lvl == 2) ? 40500 : 42525;

    const float ox = __shfl(offv, g * 2);
    const float oy = __shfl(offv, g * 2 + 1);
    const float aw = __shfl(attw, g);
    const float rx = __shfl(refv, lvl * 2);
    const float ry = __shfl(refv, lvl * 2 + 1);

    const float fLW = (float)LW;
    const float x = fmaf(rx, fLW, ox) - 0.5f;
    const float y = fmaf(ry, fLW, oy) - 0.5f;
    const float x0f = floorf(x), y0f = floorf(y);
    const float dx = x - x0f, dy = y - y0f;
    const int x0 = (int)x0f, y0 = (int)y0f;
    const int x1 = x0 + 1, y1 = y0 + 1;

    const bool vx0 = (x0 >= 0) && (x0 < LW);
    const bool vx1 = (x1 >= 0) && (x1 < LW);
    const bool vy0 = (y0 >= 0) && (y0 < LW);
    const bool vy1 = (y1 >= 0) && (y1 < LW);

    const int x0c = min(max(x0, 0), LW - 1);
    const int x1c = min(max(x1, 0), LW - 1);
    const int y0c = min(max(y0, 0), LW - 1);
    const int y1c = min(max(y1, 0), LW - 1);

    const float wx0 = 1.f - dx, wy0 = 1.f - dy;
    float w00 = wx0 * wy0 * aw;
    float w10 = dx  * wy0 * aw;
    float w01 = wx0 * dy  * aw;
    float w11 = dx  * dy  * aw;
    w00 = (vx0 && vy0) ? w00 : 0.f;
    w10 = (vx1 && vy0) ? w10 : 0.f;
    w01 = (vx0 && vy1) ? w01 : 0.f;
    w11 = (vx1 && vy1) ? w11 : 0.f;

    const unsigned short* __restrict__ vb = value + h * 32 + j * 8;
    const int r0 = LS + y0c * LW;
    const int r1 = LS + y1c * LW;
    const ushort8 v00 = *(const ushort8*)(vb + (size_t)(r0 + x0c) * 256);
    const ushort8 v10 = *(const ushort8*)(vb + (size_t)(r0 + x1c) * 256);
    const ushort8 v01 = *(const ushort8*)(vb + (size_t)(r1 + x0c) * 256);
    const ushort8 v11 = *(const ushort8*)(vb + (size_t)(r1 + x1c) * 256);

    float acc[8];
    #pragma unroll
    for (int e2 = 0; e2 < 8; ++e2) {
        float s = w00 * bf16_to_f32(v00[e2]);
        s = fmaf(w10, bf16_to_f32(v10[e2]), s);
        s = fmaf(w01, bf16_to_f32(v01[e2]), s);
        s = fmaf(w11, bf16_to_f32(v11[e2]), s);
        acc[e2] = s;
    }

    #pragma unroll
    for (int msk = 4; msk <= 32; msk <<= 1)
        #pragma unroll
        for (int e2 = 0; e2 < 8; ++e2)
            acc[e2] += __shfl_xor(acc[e2], msk);

    if (g == 0) {
        ushort8 o;
        #pragma unroll
        for (int e2 = 0; e2 < 8; ++e2) o[e2] = f32_to_bf16_rne(acc[e2]);
        *(ushort8*)(tmp + (size_t)q * 256 + h * 32 + j * 8) = o;
    }
}

// ---------------------------------------------------------------------------
extern "C" void kernel_launch(void* const* d_in, const int* in_sizes, int n_in,
                              void* d_out, int out_size, void* d_ws, size_t ws_size,
                              hipStream_t stream)
{
    const float* query    = (const float*)d_in[0];
    const float* value_in = (const float*)d_in[1];
    const float* refp     = (const float*)d_in[2];
    const float* Wv = (const float*)d_in[3];
    const float* bv = (const float*)d_in[4];
    const float* Ws = (const float*)d_in[5];
    const float* bs = (const float*)d_in[6];
    const float* Wa = (const float*)d_in[7];
    const float* ba = (const float*)d_in[8];
    const float* Wo = (const float*)d_in[9];
    const float* bo = (const float*)d_in[10];
    float* out = (float*)d_out;

    // workspace layout (bytes)
    char* p = (char*)d_ws;
    const size_t SZ_BF = (size_t)QLEN * 256 * 2;   // 22,043,648
    unsigned short* q_bf   = (unsigned short*)p;               p += SZ_BF;
    unsigned short* vin_bf = (unsigned short*)p;               p += SZ_BF;  // reused as tmp_bf
    unsigned short* val_bf = (unsigned short*)p;               p += SZ_BF;
    float*          offs   = (float*)p;                        p += (size_t)QLEN * 256 * 4;
    float*          attl   = (float*)p;                        p += (size_t)QLEN * 128 * 4;
    unsigned short* wtv_h  = (unsigned short*)p;               p += 256 * 256 * 2;
    unsigned short* wtv_l  = (unsigned short*)p;               p += 256 * 256 * 2;
    unsigned short* wts_h  = (unsigned short*)p;               p += 256 * 256 * 2;
    unsigned short* wts_l  = (unsigned short*)p;               p += 256 * 256 * 2;
    unsigned short* wta_h  = (unsigned short*)p;               p += 128 * 256 * 2;
    unsigned short* wta_l  = (unsigned short*)p;               p += 128 * 256 * 2;
    unsigned short* wto_h  = (unsigned short*)p;               p += 256 * 256 * 2;
    unsigned short* wto_l  = (unsigned short*)p;               p += 256 * 256 * 2;
    unsigned short* tmp_bf = vin_bf;   // lifetime-disjoint reuse

    const dim3 blk(256);
    const int MT = (QLEN + 127) / 128;   // 337
    const int n4 = QLEN * 256 / 4;

    // pre-passes
    w_split<<<256, blk, 0, stream>>>(Wv, wtv_h, wtv_l, 256);
    w_split<<<256, blk, 0, stream>>>(Ws, wts_h, wts_l, 256);
    w_split<<<128, blk, 0, stream>>>(Wa, wta_h, wta_l, 128);
    w_split<<<256, blk, 0, stream>>>(Wo, wto_h, wto_l, 256);
    cvt_bf16<<<1024, blk, 0, stream>>>(query,    q_bf,   n4);
    cvt_bf16<<<1024, blk, 0, stream>>>(value_in, vin_bf, n4);

    // GEMMs (LDS-staged MFMA)
    gemm_mfma_lds<<<dim3(MT, 2), blk, 0, stream>>>(vin_bf, wtv_h, wtv_l, bv,
                                                   nullptr, val_bf, QLEN, 256, 1);
    gemm_mfma_lds<<<dim3(MT, 2), blk, 0, stream>>>(q_bf, wts_h, wts_l, bs,
                                                   offs, nullptr, QLEN, 256, 0);
    gemm_mfma_lds<<<dim3(MT, 1), blk, 0, stream>>>(q_bf, wta_h, wta_l, ba,
                                                   attl, nullptr, QLEN, 128, 0);

    // sampler
    const int nwaves = QLEN * 8;
    msda_sample<<<dim3((nwaves + 3) / 4), blk, 0, stream>>>(val_bf, offs, attl, refp, tmp_bf);

    // output projection
    gemm_mfma_lds<<<dim3(MT, 2), blk, 0, stream>>>(tmp_bf, wto_h, wto_l, bo,
                                                   out, nullptr, QLEN, 256, 0);
}

// Round 5
// 376.749 us; speedup vs baseline: 1.7620x; 1.0929x over previous
//
#include <hip/hip_runtime.h>
#include <hip/hip_bf16.h>
#include <cstddef>

#define QLEN 43054

typedef __attribute__((ext_vector_type(8))) short short8;
typedef __attribute__((ext_vector_type(8))) unsigned short ushort8;
typedef __attribute__((ext_vector_type(4))) float f32x4;

#if defined(__has_builtin)
#if __has_builtin(__builtin_amdgcn_fdot2_f32_bf16)
#define MSDA_DOT2 1
typedef __attribute__((ext_vector_type(2))) __bf16 bf16x2;
#endif
#endif

__device__ __forceinline__ unsigned short f32_to_bf16_rne(float f) {
    unsigned int u = __float_as_uint(f);
    unsigned int r = (u + 0x7fffu + ((u >> 16) & 1u)) >> 16;
    return (unsigned short)r;
}
__device__ __forceinline__ float bf16_to_f32(unsigned short h) {
    return __uint_as_float(((unsigned int)h) << 16);
}

// ---------------------------------------------------------------------------
// Merged weight transpose + hi/lo split (coalesced via LDS 32x32 tiles).
// Wv[256][256]->wtv, Ws[256][256]->wtsa rows 0..255, Wa[256][128]->wtsa rows
// 256..383, Wo[256][256]->wto.  224 blocks total.
// ---------------------------------------------------------------------------
__global__ __launch_bounds__(256) void w_split_all(
    const float* __restrict__ Wv, const float* __restrict__ Ws,
    const float* __restrict__ Wa, const float* __restrict__ Wo,
    unsigned short* __restrict__ wtv_h, unsigned short* __restrict__ wtv_l,
    unsigned short* __restrict__ wtsa_h, unsigned short* __restrict__ wtsa_l,
    unsigned short* __restrict__ wto_h, unsigned short* __restrict__ wto_l)
{
    const int b = blockIdx.x;
    const int tid = threadIdx.x;
    const float* W; unsigned short *hi, *lo; int N, n0add = 0, t;
    if (b < 64)       { W = Wv; hi = wtv_h;  lo = wtv_l;  N = 256; t = b; }
    else if (b < 128) { W = Ws; hi = wtsa_h; lo = wtsa_l; N = 256; t = b - 64; }
    else if (b < 160) { W = Wa; hi = wtsa_h; lo = wtsa_l; N = 128; t = b - 128; n0add = 256; }
    else              { W = Wo; hi = wto_h;  lo = wto_l;  N = 256; t = b - 160; }
    const int kt = t & 7, nt = t >> 3;
    const int k0 = kt * 32, n0 = nt * 32;

    __shared__ float T[32][33];
    const int r = tid >> 3;            // 0..31
    const int c4 = (tid & 7) * 4;      // 0..28
    const float4 v = *(const float4*)(W + (size_t)(k0 + r) * N + n0 + c4);
    T[r][c4 + 0] = v.x; T[r][c4 + 1] = v.y; T[r][c4 + 2] = v.z; T[r][c4 + 3] = v.w;
    __syncthreads();

    const int n = r;                   // output row within tile
    ushort4 oh, ol;
    #pragma unroll
    for (int i = 0; i < 4; ++i) {
        const float w = T[c4 + i][n];
        const unsigned short h = f32_to_bf16_rne(w);
        ((unsigned short*)&oh)[i] = h;
        ((unsigned short*)&ol)[i] = f32_to_bf16_rne(w - bf16_to_f32(h));
    }
    const size_t ob = (size_t)(n0add + n0 + n) * 256 + k0 + c4;
    *(ushort4*)(hi + ob) = oh;
    *(ushort4*)(lo + ob) = ol;
}

// ---------------------------------------------------------------------------
// Merged f32 -> bf16 for query and value_in.
// ---------------------------------------------------------------------------
__global__ __launch_bounds__(256) void cvt_all(
    const float* __restrict__ a, const float* __restrict__ b,
    unsigned short* __restrict__ oa, unsigned short* __restrict__ ob)
{
    const int n4 = QLEN * 64;
    int i = blockIdx.x * 256 + threadIdx.x;
    const int stride = gridDim.x * 256;
    for (; i < 2 * n4; i += stride) {
        const float4 v = (i < n4) ? ((const float4*)a)[i] : ((const float4*)b)[i - n4];
        ushort4 o;
        o.x = f32_to_bf16_rne(v.x);
        o.y = f32_to_bf16_rne(v.y);
        o.z = f32_to_bf16_rne(v.z);
        o.w = f32_to_bf16_rne(v.w);
        if (i < n4) ((ushort4*)oa)[i] = o;
        else        ((ushort4*)ob)[i - n4] = o;
    }
}

// ---------------------------------------------------------------------------
// 2-phase double-buffered LDS MFMA GEMM: C = A_bf16[M,256] @ (Bh+Bl) + bias.
// Block 128x128 (4 waves), BK=32, K=256. Staging via global_load_lds w=16,
// XOR-swizzled source (rule #21). One barrier per K-step; next-tile loads
// stay in flight under current-tile ds_read+MFMA (catalog T3 minimum).
// bias: cols < n1 from bias1, else bias2[col-n1].
// mode 0: f32 out (ld N); mode 1: bf16 out (ld 256).
// ---------------------------------------------------------------------------
__global__ __launch_bounds__(256) void gemm_mfma_db(
    const unsigned short* __restrict__ A,
    const unsigned short* __restrict__ Bh,
    const unsigned short* __restrict__ Bl,
    const float* __restrict__ bias1, const float* __restrict__ bias2,
    float* __restrict__ Cf, unsigned short* __restrict__ Cb,
    int M, int N, int n1, int mode)
{
    __shared__ alignas(16) unsigned short As[2][4096];
    __shared__ alignas(16) unsigned short Bhs[2][4096];
    __shared__ alignas(16) unsigned short Bls[2][4096];

    const int tid = threadIdx.x;
    const int lane = tid & 63;
    const int w = tid >> 6;
    const int wm = (w >> 1) * 64;
    const int wn = (w & 1) * 64;
    const int bm = blockIdx.x * 128;
    const int bn = blockIdx.y * 128;

    const int rl = lane >> 2;        // staging row within issue (0..15)
    const int cd = lane & 3;         // staging dest 16B-column
    const int fr = lane & 15;        // fragment row
    const int fc = lane >> 4;        // fragment k-block

    auto stage = [&](int buf, int k0) {
        #pragma unroll
        for (int i = 0; i < 2; ++i) {
            const int ii = w * 2 + i;
            const int row = ii * 16 + rl;
            const int cs = cd ^ ((row >> 1) & 3);
            const size_t gof = (size_t)k0 + cs * 8;
            const int ra = min(bm + row, M - 1);
            const int rb = bn + row;
            __builtin_amdgcn_global_load_lds(
                (const unsigned int*)(A + (size_t)ra * 256 + gof),
                (unsigned int*)&As[buf][ii * 512], 16, 0, 0);
            __builtin_amdgcn_global_load_lds(
                (const unsigned int*)(Bh + (size_t)rb * 256 + gof),
                (unsigned int*)&Bhs[buf][ii * 512], 16, 0, 0);
            __builtin_amdgcn_global_load_lds(
                (const unsigned int*)(Bl + (size_t)rb * 256 + gof),
                (unsigned int*)&Bls[buf][ii * 512], 16, 0, 0);
        }
    };

    f32x4 acc[4][4];
    #pragma unroll
    for (int i = 0; i < 4; ++i)
        #pragma unroll
        for (int j = 0; j < 4; ++j)
            acc[i][j] = (f32x4){0.f, 0.f, 0.f, 0.f};

    stage(0, 0);
    __syncthreads();
    int cur = 0;

    for (int t = 0; t < 8; ++t) {
        if (t < 7) stage(cur ^ 1, (t + 1) * 32);

        short8 a[4], bh4[4], bl4[4];
        #pragma unroll
        for (int f = 0; f < 4; ++f) {
            const int rowA = wm + f * 16 + fr;
            const int pcA = fc ^ ((rowA >> 1) & 3);
            a[f] = *(const short8*)&As[cur][rowA * 32 + pcA * 8];
            const int rowB = wn + f * 16 + fr;
            const int pcB = fc ^ ((rowB >> 1) & 3);
            bh4[f] = *(const short8*)&Bhs[cur][rowB * 32 + pcB * 8];
            bl4[f] = *(const short8*)&Bls[cur][rowB * 32 + pcB * 8];
        }

        #pragma unroll
        for (int i = 0; i < 4; ++i)
            #pragma unroll
            for (int j = 0; j < 4; ++j) {
                acc[i][j] = __builtin_amdgcn_mfma_f32_16x16x32_bf16(a[i], bh4[j], acc[i][j], 0, 0, 0);
                acc[i][j] = __builtin_amdgcn_mfma_f32_16x16x32_bf16(a[i], bl4[j], acc[i][j], 0, 0, 0);
            }

        if (t < 7) { __syncthreads(); cur ^= 1; }
    }

    float bv[4];
    #pragma unroll
    for (int j = 0; j < 4; ++j) {
        const int col = bn + wn + j * 16 + fr;
        bv[j] = (col < n1) ? bias1[col] : bias2[col - n1];
    }

    const int rbase = bm + wm + fc * 4;
    if (mode == 0) {
        #pragma unroll
        for (int i = 0; i < 4; ++i)
            #pragma unroll
            for (int r = 0; r < 4; ++r) {
                const int row = rbase + i * 16 + r;
                if (row < M) {
                    #pragma unroll
                    for (int j = 0; j < 4; ++j) {
                        const int col = bn + wn + j * 16 + fr;
                        Cf[(size_t)row * N + col] = acc[i][j][r] + bv[j];
                    }
                }
            }
    } else {
        #pragma unroll
        for (int i = 0; i < 4; ++i)
            #pragma unroll
            for (int r = 0; r < 4; ++r) {
                const int row = rbase + i * 16 + r;
                if (row < M) {
                    #pragma unroll
                    for (int j = 0; j < 4; ++j) {
                        const int col = bn + wn + j * 16 + fr;
                        Cb[(size_t)row * 256 + col] = f32_to_bf16_rne(acc[i][j][r] + bv[j]);
                    }
                }
            }
    }
}

// ---------------------------------------------------------------------------
// Fused softmax + multi-scale deformable sampling, v4.
// One wave per (q,h): lanes = 16 points x 4 channel-octets.
// oa : [LEN][384] f32 (cols 0..255 offsets, 256..383 attn logits)
// value/tmp : [LEN][8][32] bf16.  Corner combine via v_dot2_f32_bf16.
// ---------------------------------------------------------------------------
__global__ __launch_bounds__(256) void msda_sample(
    const unsigned short* __restrict__ value,
    const float* __restrict__ oa,
    const float* __restrict__ refp,
    unsigned short* __restrict__ tmp)
{
    const int wv = (blockIdx.x << 2) + (threadIdx.x >> 6);
    const int lane = threadIdx.x & 63;
    const int q = wv >> 3;
    const int h = wv & 7;
    if (q >= QLEN) return;

    const int g = lane >> 2;      // point index 0..15  (level = g>>2)
    const int j = lane & 3;       // channel octet

    const float offv  = oa[(size_t)q * 384 + h * 32 + (lane & 31)];
    const float logit = oa[(size_t)q * 384 + 256 + h * 16 + (lane & 15)];
    const float refv  = refp[(size_t)q * 8 + (lane & 7)];

    float mx = logit;
    #pragma unroll
    for (int msk = 1; msk < 16; msk <<= 1) mx = fmaxf(mx, __shfl_xor(mx, msk));
    const float e = __expf(logit - mx);
    float sm = e;
    #pragma unroll
    for (int msk = 1; msk < 16; msk <<= 1) sm += __shfl_xor(sm, msk);
    const float attw = e * __builtin_amdgcn_rcpf(sm);

    const int lvl = g >> 2;
    const int LW = (lvl == 0) ? 180 : (lvl == 1) ? 90 : (lvl == 2) ? 45 : 23;
    const int LS = (lvl == 0) ? 0 : (lvl == 1) ? 32400 : (lvl == 2) ? 40500 : 42525;

    const float ox = __shfl(offv, g * 2);
    const float oy = __shfl(offv, g * 2 + 1);
    const float aw = __shfl(attw, g);
    const float rx = __shfl(refv, lvl * 2);
    const float ry = __shfl(refv, lvl * 2 + 1);

    const float fLW = (float)LW;
    const float x = fmaf(rx, fLW, ox) - 0.5f;
    const float y = fmaf(ry, fLW, oy) - 0.5f;
    const float x0f = floorf(x), y0f = floorf(y);
    const float dx = x - x0f, dy = y - y0f;
    const int x0 = (int)x0f, y0 = (int)y0f;
    const int x1 = x0 + 1, y1 = y0 + 1;

    const bool vx0 = (x0 >= 0) && (x0 < LW);
    const bool vx1 = (x1 >= 0) && (x1 < LW);
    const bool vy0 = (y0 >= 0) && (y0 < LW);
    const bool vy1 = (y1 >= 0) && (y1 < LW);

    const int x0c = min(max(x0, 0), LW - 1);
    const int x1c = min(max(x1, 0), LW - 1);
    const int y0c = min(max(y0, 0), LW - 1);
    const int y1c = min(max(y1, 0), LW - 1);

    const float wx0 = 1.f - dx, wy0 = 1.f - dy;
    float w00 = wx0 * wy0 * aw;
    float w10 = dx  * wy0 * aw;
    float w01 = wx0 * dy  * aw;
    float w11 = dx  * dy  * aw;
    w00 = (vx0 && vy0) ? w00 : 0.f;
    w10 = (vx1 && vy0) ? w10 : 0.f;
    w01 = (vx0 && vy1) ? w01 : 0.f;
    w11 = (vx1 && vy1) ? w11 : 0.f;

    const unsigned short* __restrict__ vb = value + h * 32 + j * 8;
    const int r0 = LS + y0c * LW;
    const int r1 = LS + y1c * LW;

    float acc[8];

#ifdef MSDA_DOT2
    const uint4 u00 = *(const uint4*)(vb + (size_t)(r0 + x0c) * 256);
    const uint4 u10 = *(const uint4*)(vb + (size_t)(r0 + x1c) * 256);
    const uint4 u01 = *(const uint4*)(vb + (size_t)(r1 + x0c) * 256);
    const uint4 u11 = *(const uint4*)(vb + (size_t)(r1 + x1c) * 256);
    const unsigned int U00[4] = {u00.x, u00.y, u00.z, u00.w};
    const unsigned int U10[4] = {u10.x, u10.y, u10.z, u10.w};
    const unsigned int U01[4] = {u01.x, u01.y, u01.z, u01.w};
    const unsigned int U11[4] = {u11.x, u11.y, u11.z, u11.w};

    const unsigned int wau =
        ((unsigned int)f32_to_bf16_rne(w10) << 16) | f32_to_bf16_rne(w00);
    const unsigned int wbu =
        ((unsigned int)f32_to_bf16_rne(w11) << 16) | f32_to_bf16_rne(w01);
    const bf16x2 WA = __builtin_bit_cast(bf16x2, wau);
    const bf16x2 WB = __builtin_bit_cast(bf16x2, wbu);

    #pragma unroll
    for (int e2 = 0; e2 < 4; ++e2) {
        const unsigned p_lo = __builtin_amdgcn_perm(U10[e2], U00[e2], 0x05040100u);
        const unsigned p_hi = __builtin_amdgcn_perm(U10[e2], U00[e2], 0x07060302u);
        const unsigned q_lo = __builtin_amdgcn_perm(U11[e2], U01[e2], 0x05040100u);
        const unsigned q_hi = __builtin_amdgcn_perm(U11[e2], U01[e2], 0x07060302u);
        float s0 = __builtin_amdgcn_fdot2_f32_bf16(__builtin_bit_cast(bf16x2, p_lo), WA, 0.f, false);
        s0 = __builtin_amdgcn_fdot2_f32_bf16(__builtin_bit_cast(bf16x2, q_lo), WB, s0, false);
        float s1 = __builtin_amdgcn_fdot2_f32_bf16(__builtin_bit_cast(bf16x2, p_hi), WA, 0.f, false);
        s1 = __builtin_amdgcn_fdot2_f32_bf16(__builtin_bit_cast(bf16x2, q_hi), WB, s1, false);
        acc[2 * e2] = s0;
        acc[2 * e2 + 1] = s1;
    }
#else
    const ushort8 v00 = *(const ushort8*)(vb + (size_t)(r0 + x0c) * 256);
    const ushort8 v10 = *(const ushort8*)(vb + (size_t)(r0 + x1c) * 256);
    const ushort8 v01 = *(const ushort8*)(vb + (size_t)(r1 + x0c) * 256);
    const ushort8 v11 = *(const ushort8*)(vb + (size_t)(r1 + x1c) * 256);
    #pragma unroll
    for (int e2 = 0; e2 < 8; ++e2) {
        float s = w00 * bf16_to_f32(v00[e2]);
        s = fmaf(w10, bf16_to_f32(v10[e2]), s);
        s = fmaf(w01, bf16_to_f32(v01[e2]), s);
        s = fmaf(w11, bf16_to_f32(v11[e2]), s);
        acc[e2] = s;
    }
#endif

    #pragma unroll
    for (int msk = 4; msk <= 32; msk <<= 1)
        #pragma unroll
        for (int e2 = 0; e2 < 8; ++e2)
            acc[e2] += __shfl_xor(acc[e2], msk);

    if (g == 0) {
        ushort8 o;
        #pragma unroll
        for (int e2 = 0; e2 < 8; ++e2) o[e2] = f32_to_bf16_rne(acc[e2]);
        *(ushort8*)(tmp + (size_t)q * 256 + h * 32 + j * 8) = o;
    }
}

// ---------------------------------------------------------------------------
extern "C" void kernel_launch(void* const* d_in, const int* in_sizes, int n_in,
                              void* d_out, int out_size, void* d_ws, size_t ws_size,
                              hipStream_t stream)
{
    const float* query    = (const float*)d_in[0];
    const float* value_in = (const float*)d_in[1];
    const float* refp     = (const float*)d_in[2];
    const float* Wv = (const float*)d_in[3];
    const float* bv = (const float*)d_in[4];
    const float* Ws = (const float*)d_in[5];
    const float* bs = (const float*)d_in[6];
    const float* Wa = (const float*)d_in[7];
    const float* ba = (const float*)d_in[8];
    const float* Wo = (const float*)d_in[9];
    const float* bo = (const float*)d_in[10];
    float* out = (float*)d_out;

    // workspace layout (bytes)
    char* p = (char*)d_ws;
    const size_t SZ_BF = (size_t)QLEN * 256 * 2;
    unsigned short* q_bf   = (unsigned short*)p;  p += SZ_BF;
    unsigned short* vin_bf = (unsigned short*)p;  p += SZ_BF;   // reused as tmp_bf
    unsigned short* val_bf = (unsigned short*)p;  p += SZ_BF;
    float*          oaB    = (float*)p;           p += (size_t)QLEN * 384 * 4;
    unsigned short* wtv_h  = (unsigned short*)p;  p += 256 * 256 * 2;
    unsigned short* wtv_l  = (unsigned short*)p;  p += 256 * 256 * 2;
    unsigned short* wtsa_h = (unsigned short*)p;  p += 384 * 256 * 2;
    unsigned short* wtsa_l = (unsigned short*)p;  p += 384 * 256 * 2;
    unsigned short* wto_h  = (unsigned short*)p;  p += 256 * 256 * 2;
    unsigned short* wto_l  = (unsigned short*)p;  p += 256 * 256 * 2;
    unsigned short* tmp_bf = vin_bf;

    const dim3 blk(256);
    const int MT = (QLEN + 127) / 128;   // 337

    w_split_all<<<224, blk, 0, stream>>>(Wv, Ws, Wa, Wo, wtv_h, wtv_l,
                                         wtsa_h, wtsa_l, wto_h, wto_l);
    cvt_all<<<2048, blk, 0, stream>>>(query, value_in, q_bf, vin_bf);

    gemm_mfma_db<<<dim3(MT, 2), blk, 0, stream>>>(vin_bf, wtv_h, wtv_l, bv, bv,
                                                  nullptr, val_bf, QLEN, 256, 256, 1);
    gemm_mfma_db<<<dim3(MT, 3), blk, 0, stream>>>(q_bf, wtsa_h, wtsa_l, bs, ba,
                                                  oaB, nullptr, QLEN, 384, 256, 0);

    const int nwaves = QLEN * 8;
    msda_sample<<<dim3((nwaves + 3) / 4), blk, 0, stream>>>(val_bf, oaB, refp, tmp_bf);

    gemm_mfma_db<<<dim3(MT, 2), blk, 0, stream>>>(tmp_bf, wto_h, wto_l, bo, bo,
                                                  out, nullptr, QLEN, 256, 256, 0);
}